// Round 3
// baseline (231.202 us; speedup 1.0000x reference)
//
#include <hip/hip_runtime.h>

// Problem constants (from reference setup_inputs)
constexpr int B = 4, C = 96, H = 192, W = 320;
constexpr int HW      = H * W;       // 61440 floats per (b,c) plane
constexpr int HW4     = HW / 4;      // 15360 float4 per (b,c) plane
constexpr int OUT_CH  = 81;

// ---- stage A tiling (channel-split partial reduction, contiguous bursts) ----
constexpr int PART = 4;              // channel partials
constexpr int CPP  = C / PART;       // 24 channels per partial
constexpr int SC   = 256;            // spatial float4 per block -> 4 KB burst per channel step
constexpr int SCH  = HW4 / SC;       // 60 spatial chunks per (b)
constexpr int TOTAL_S4 = B * HW4;    // 61440 corr float4s

// ---- phase 2 tiling ----
constexpr int OCH     = 27;              // out-channels per block
constexpr int OCB     = OUT_CH / OCH;    // 3 o-chunks
constexpr int S4PB    = 256;             // spatial f4 per phase2 block
constexpr int SCHUNKS = HW4 / S4PB;      // 60 spatial chunks per (b)

typedef float f32x4 __attribute__((ext_vector_type(4)));

#define ACC(X, Y)                                                     \
    d.x = fmaf((X).x, (Y).x, d.x); d.y = fmaf((X).y, (Y).y, d.y);     \
    d.z = fmaf((X).z, (Y).z, d.z); d.w = fmaf((X).w, (Y).w, d.w);     \
    a.x += fabsf((X).x); a.y += fabsf((X).y);                         \
    a.z += fabsf((X).z); a.w += fabsf((X).w);

// ---------------- Stage A: partial dot/asum with 4-KB contiguous bursts ------
// Block = (b, p, sc): 256 threads each own ONE spatial float4 and loop the
// partial's 24 channels. Each channel step reads a 4-KB contiguous span of f1
// and f2 (vs 512 B in the previous structure) -> copy-like DRAM page locality.
// Consecutive blocks (sc innermost) cover adjacent 4-KB chunks of the same
// channel set, so co-resident blocks form long linear streams.
// Partials stored interleaved: part[(p*B+b)*HW4 + s4] = {dot, asum} pairs.
__global__ __launch_bounds__(256) void corr_stageA(
    const f32x4* __restrict__ f1,
    const f32x4* __restrict__ f2,
    f32x4* __restrict__ part)           // [PART*B*HW4][2] f32x4 pairs
{
    const int bid = blockIdx.x;          // b*PART*SCH + p*SCH + sc
    const int sc  = bid % SCH;
    const int t   = bid / SCH;
    const int p   = t % PART;
    const int b   = t / PART;
    const int s4  = sc * SC + (int)threadIdx.x;

    const f32x4* __restrict__ p1 = f1 + ((size_t)(b * C + p * CPP)) * HW4 + s4;
    const f32x4* __restrict__ p2 = f2 + ((size_t)(b * C + p * CPP)) * HW4 + s4;

    f32x4 d = {0.f, 0.f, 0.f, 0.f};
    f32x4 a = {0.f, 0.f, 0.f, 0.f};

    // 6 batches of 4 channel-pairs; 8 float4 loads issued per batch.
#pragma unroll 1
    for (int j0 = 0; j0 < CPP; j0 += 4) {
        const f32x4 x0 = p1[(size_t)(j0 + 0) * HW4];
        const f32x4 x1 = p1[(size_t)(j0 + 1) * HW4];
        const f32x4 x2 = p1[(size_t)(j0 + 2) * HW4];
        const f32x4 x3 = p1[(size_t)(j0 + 3) * HW4];
        const f32x4 y0 = p2[(size_t)(j0 + 0) * HW4];
        const f32x4 y1 = p2[(size_t)(j0 + 1) * HW4];
        const f32x4 y2 = p2[(size_t)(j0 + 2) * HW4];
        const f32x4 y3 = p2[(size_t)(j0 + 3) * HW4];
        ACC(x0, y0)
        ACC(x1, y1)
        ACC(x2, y2)
        ACC(x3, y3)
    }

    const size_t o = (((size_t)(p * B + b)) * HW4 + s4) * 2;
    part[o]     = d;    // regular stores: partials stay in L2/L3 for stage B
    part[o + 1] = a;
}

// ---------------- Stage B: reduce 4 partials -> corr map --------------------
// 240 blocks; reads 7.9 MB (L2/L3-resident), writes the 983-KB corr map.
__global__ __launch_bounds__(256) void corr_stageB(
    const f32x4* __restrict__ part,
    f32x4* __restrict__ corr)
{
    const int idx = blockIdx.x * 256 + (int)threadIdx.x;   // [0, TOTAL_S4)
    f32x4 dt = {0.f, 0.f, 0.f, 0.f};
    f32x4 at = {0.f, 0.f, 0.f, 0.f};
#pragma unroll
    for (int p = 0; p < PART; ++p) {
        const size_t o = ((size_t)p * TOTAL_S4 + idx) * 2;
        const f32x4 dk = part[o];
        const f32x4 ak = part[o + 1];
        dt.x += dk.x; dt.y += dk.y; dt.z += dk.z; dt.w += dk.w;
        at.x += ak.x; at.y += ak.y; at.z += ak.z; at.w += ak.w;
    }
    const float inv_c = 1.0f / (float)C;
    f32x4 r;
    r.x = (at.x > 0.1f) ? dt.x * inv_c : 0.0f;
    r.y = (at.y > 0.1f) ? dt.y * inv_c : 0.0f;
    r.z = (at.z > 0.1f) ? dt.z * inv_c : 0.0f;
    r.w = (at.w > 0.1f) ? dt.w * inv_c : 0.0f;
    corr[idx] = r;
}

// ---------------- Phase 2: broadcast (writes-dominated) ----------------
// Each thread reads its corr f32x4 ONCE and issues 27 independent NT stores.
__global__ __launch_bounds__(256) void corr_phase2(
    const f32x4* __restrict__ corr,
    f32x4* __restrict__ out)
{
    const int bid = blockIdx.x;          // [0, B*SCHUNKS*OCB)
    const int oc  = bid % OCB;
    const int t   = bid / OCB;
    const int b   = t / SCHUNKS;
    const int sc  = t - b * SCHUNKS;
    const int s4  = sc * S4PB + (int)threadIdx.x;

    const f32x4 r = corr[(size_t)b * HW4 + s4];
    f32x4* __restrict__ po = out + ((size_t)(b * OUT_CH + oc * OCH)) * HW4 + s4;
#pragma unroll
    for (int o = 0; o < OCH; ++o)
        __builtin_nontemporal_store(r, po + (size_t)o * HW4);
}

// ---------------- Fallback A (ws fits corr only): previous 2-phase ----------
constexpr int GROUPS = 8;
constexpr int CPG    = C / GROUPS;
constexpr int SPB    = 32;

__global__ __launch_bounds__(256) void corr_phase1(
    const f32x4* __restrict__ f1,
    const f32x4* __restrict__ f2,
    f32x4* __restrict__ corr)
{
    __shared__ f32x4 sdot[GROUPS][SPB];
    __shared__ f32x4 sasum[GROUPS][SPB];

    const int s_local = threadIdx.x & (SPB - 1);
    const int g       = threadIdx.x >> 5;
    const int base4   = blockIdx.x * SPB;
    const int b       = base4 / HW4;
    const int splane  = (base4 - b * HW4) + s_local;

    const f32x4* __restrict__ p1 = f1 + ((size_t)(b * C + g * CPG)) * HW4 + splane;
    const f32x4* __restrict__ p2 = f2 + ((size_t)(b * C + g * CPG)) * HW4 + splane;

    f32x4 d = {0.f, 0.f, 0.f, 0.f};
    f32x4 a = {0.f, 0.f, 0.f, 0.f};

#pragma unroll 1
    for (int j0 = 0; j0 < CPG; j0 += 4) {
        const f32x4 x0 = p1[(size_t)(j0 + 0) * HW4];
        const f32x4 x1 = p1[(size_t)(j0 + 1) * HW4];
        const f32x4 x2 = p1[(size_t)(j0 + 2) * HW4];
        const f32x4 x3 = p1[(size_t)(j0 + 3) * HW4];
        const f32x4 y0 = p2[(size_t)(j0 + 0) * HW4];
        const f32x4 y1 = p2[(size_t)(j0 + 1) * HW4];
        const f32x4 y2 = p2[(size_t)(j0 + 2) * HW4];
        const f32x4 y3 = p2[(size_t)(j0 + 3) * HW4];
        ACC(x0, y0)
        ACC(x1, y1)
        ACC(x2, y2)
        ACC(x3, y3)
    }

    sdot[g][s_local]  = d;
    sasum[g][s_local] = a;
    __syncthreads();

    if (g == 0) {
        f32x4 dt = sdot[0][s_local];
        f32x4 at = sasum[0][s_local];
#pragma unroll
        for (int k = 1; k < GROUPS; ++k) {
            const f32x4 dk = sdot[k][s_local];
            const f32x4 ak = sasum[k][s_local];
            dt.x += dk.x; dt.y += dk.y; dt.z += dk.z; dt.w += dk.w;
            at.x += ak.x; at.y += ak.y; at.z += ak.z; at.w += ak.w;
        }
        const float inv_c = 1.0f / (float)C;
        f32x4 r;
        r.x = (at.x > 0.1f) ? dt.x * inv_c : 0.0f;
        r.y = (at.y > 0.1f) ? dt.y * inv_c : 0.0f;
        r.z = (at.z > 0.1f) ? dt.z * inv_c : 0.0f;
        r.w = (at.w > 0.1f) ? dt.w * inv_c : 0.0f;
        corr[base4 + s_local] = r;
    }
}

// ---------------- Fallback B (tiny ws): single kernel -----------------------
__global__ __launch_bounds__(256) void spike_corr_mono(
    const float* __restrict__ f1,
    const float* __restrict__ f2,
    float* __restrict__ out)
{
    const int idx = blockIdx.x * blockDim.x + threadIdx.x;
    const int b = idx / HW;
    const int s = idx - b * HW;
    const float* __restrict__ p1 = f1 + (size_t)b * C * HW + s;
    const float* __restrict__ p2 = f2 + (size_t)b * C * HW + s;
    float dot = 0.f, asum = 0.f;
#pragma unroll 16
    for (int c = 0; c < C; ++c) {
        const float a = p1[(size_t)c * HW];
        const float v = p2[(size_t)c * HW];
        dot = fmaf(a, v, dot);
        asum += fabsf(a);
    }
    const float r = (asum > 0.1f) ? dot * (1.0f / (float)C) : 0.0f;
    float* __restrict__ po = out + (size_t)b * OUT_CH * HW + s;
#pragma unroll 1
    for (int o = 0; o < OUT_CH; ++o)
        __builtin_nontemporal_store(r, po + (size_t)o * HW);
}

extern "C" void kernel_launch(void* const* d_in, const int* in_sizes, int n_in,
                              void* d_out, int out_size, void* d_ws, size_t ws_size,
                              hipStream_t stream) {
    const size_t corr_f4   = (size_t)TOTAL_S4;                 // 61440 f32x4
    const size_t part_f4   = (size_t)PART * TOTAL_S4 * 2;      // 491520 f32x4 (interleaved)
    const size_t corr_bytes = corr_f4 * sizeof(f32x4);         // 983,040 B
    const size_t full_bytes = (part_f4 + corr_f4) * sizeof(f32x4);  // ~8.85 MB

    if (ws_size >= full_bytes) {
        const f32x4* f1 = (const f32x4*)d_in[0];
        const f32x4* f2 = (const f32x4*)d_in[1];
        f32x4* part = (f32x4*)d_ws;
        f32x4* corr = part + part_f4;
        f32x4* out  = (f32x4*)d_out;

        corr_stageA<<<B * PART * SCH, 256, 0, stream>>>(f1, f2, part);        // 960 blocks
        corr_stageB<<<TOTAL_S4 / 256, 256, 0, stream>>>(part, corr);          // 240 blocks
        corr_phase2<<<B * SCHUNKS * OCB, 256, 0, stream>>>(corr, out);        // 720 blocks
    } else if (ws_size >= corr_bytes) {
        const f32x4* f1 = (const f32x4*)d_in[0];
        const f32x4* f2 = (const f32x4*)d_in[1];
        f32x4* corr = (f32x4*)d_ws;
        f32x4* out  = (f32x4*)d_out;

        corr_phase1<<<TOTAL_S4 / SPB, 256, 0, stream>>>(f1, f2, corr);        // 1920 blocks
        corr_phase2<<<B * SCHUNKS * OCB, 256, 0, stream>>>(corr, out);        // 720 blocks
    } else {
        const float* f1 = (const float*)d_in[0];
        const float* f2 = (const float*)d_in[1];
        float* out = (float*)d_out;
        spike_corr_mono<<<(B * HW) / 256, 256, 0, stream>>>(f1, f2, out);
    }
}

// Round 4
// 224.655 us; speedup vs baseline: 1.0291x; 1.0291x over previous
//
#include <hip/hip_runtime.h>

// Problem constants (from reference setup_inputs)
constexpr int B = 4, C = 96, H = 192, W = 320;
constexpr int HW      = H * W;       // 61440 floats per (b,c) plane
constexpr int HW4     = HW / 4;      // 15360 float4 per (b,c) plane
constexpr int OUT_CH  = 81;

// ---- fused tiling ----
constexpr int SC   = 256;            // spatial float4 per block (4 KB chunk)
constexpr int SCH  = HW4 / SC;       // 60 spatial chunks per (b)
constexpr int NBLK = B * SCH;        // 240 blocks, fully independent

typedef float f32x4 __attribute__((ext_vector_type(4)));

#define ACC(X, Y)                                                     \
    d.x = fmaf((X).x, (Y).x, d.x); d.y = fmaf((X).y, (Y).y, d.y);     \
    d.z = fmaf((X).z, (Y).z, d.z); d.w = fmaf((X).w, (Y).w, d.w);     \
    a.x += fabsf((X).x); a.y += fabsf((X).y);                         \
    a.z += fabsf((X).z); a.w += fabsf((X).w);

// ---------------- Fused: corr + 81-way broadcast in one kernel --------------
// Each block owns ONE 4-KB spatial chunk of one batch image. It reduces all
// 96 channels (8-channel load batches: 16 dwordx4 loads = 16 KB in flight per
// wave), computes the masked correlation, and immediately writes the result
// to all 81 output planes with NT stores (1 KB contiguous per wave per plane).
// No workspace, no intermediate traffic, no kernel boundaries; read-phase and
// write-phase overlap device-wide because the 240 blocks desynchronize.
__global__ __launch_bounds__(256) void spike_corr_fused(
    const f32x4* __restrict__ f1,
    const f32x4* __restrict__ f2,
    f32x4* __restrict__ out)
{
    const int base4 = blockIdx.x * SC;           // global spatial-f4 index
    const int b     = base4 / HW4;               // SC divides HW4: no straddle
    const int s4    = (base4 - b * HW4) + (int)threadIdx.x;   // in-image f4 idx

    const f32x4* __restrict__ p1 = f1 + (size_t)b * C * HW4 + s4;
    const f32x4* __restrict__ p2 = f2 + (size_t)b * C * HW4 + s4;

    f32x4 d = {0.f, 0.f, 0.f, 0.f};
    f32x4 a = {0.f, 0.f, 0.f, 0.f};

    // 12 batches of 8 channels; 16 float4 loads issued before any use.
#pragma unroll 1
    for (int c0 = 0; c0 < C; c0 += 8) {
        f32x4 x[8], y[8];
#pragma unroll
        for (int j = 0; j < 8; ++j) x[j] = p1[(size_t)(c0 + j) * HW4];
#pragma unroll
        for (int j = 0; j < 8; ++j) y[j] = p2[(size_t)(c0 + j) * HW4];
#pragma unroll
        for (int j = 0; j < 8; ++j) { ACC(x[j], y[j]) }
    }

    const float inv_c = 1.0f / (float)C;
    f32x4 r;
    r.x = (a.x > 0.1f) ? d.x * inv_c : 0.0f;
    r.y = (a.y > 0.1f) ? d.y * inv_c : 0.0f;
    r.z = (a.z > 0.1f) ? d.z * inv_c : 0.0f;
    r.w = (a.w > 0.1f) ? d.w * inv_c : 0.0f;

    // Broadcast to all 81 identical output channels. NT stores: fire-and-
    // forget, no L2/L3 pollution of the 78-MB output.
    f32x4* __restrict__ po = out + (size_t)b * OUT_CH * HW4 + s4;
#pragma unroll
    for (int o = 0; o < OUT_CH; ++o)
        __builtin_nontemporal_store(r, po + (size_t)o * HW4);
}

extern "C" void kernel_launch(void* const* d_in, const int* in_sizes, int n_in,
                              void* d_out, int out_size, void* d_ws, size_t ws_size,
                              hipStream_t stream) {
    (void)d_ws; (void)ws_size;  // fused path needs no workspace
    const f32x4* f1 = (const f32x4*)d_in[0];
    const f32x4* f2 = (const f32x4*)d_in[1];
    f32x4* out = (f32x4*)d_out;

    spike_corr_fused<<<NBLK, 256, 0, stream>>>(f1, f2, out);   // 240 blocks
}